// Round 4
// baseline (103.499 us; speedup 1.0000x reference)
//
#include <hip/hip_runtime.h>
#include <hip/hip_fp16.h>

#define B_  8
#define C_  256
#define H_  64
#define W_  64
#define G_  4
#define CG_ 64
#define K_  9
#define HW_ (H_ * W_)  // 4096

// ---------------------------------------------------------------------------
// Kernel 1: NCHW fp32 -> group-major NHWC fp16  [B,C,HW] -> [B,G,HW,CG]
// ---------------------------------------------------------------------------
__global__ __launch_bounds__(256) void to_ghwc_f16(const float* __restrict__ in,
                                                   __half* __restrict__ out) {
  __shared__ unsigned int tile[32][65];  // [channel-pair][pixel]
  const int b  = blockIdx.z;
  const int p0 = blockIdx.x * 64;
  const int g  = blockIdx.y;
  const int tid = threadIdx.x;
  const float* src = in + (size_t)b * C_ * HW_ + (size_t)g * CG_ * HW_;
  __half* dst = out + ((size_t)(b * G_ + g) * HW_) * CG_;

  const int px  = tid & 63;
  const int cp0 = tid >> 6;
#pragma unroll
  for (int i = 0; i < 8; ++i) {
    const int cp = cp0 + i * 4;
    const int c  = cp * 2;
    const float v0 = src[(size_t)c * HW_ + p0 + px];
    const float v1 = src[(size_t)(c + 1) * HW_ + p0 + px];
    const unsigned int lo = (unsigned int)__half_as_ushort(__float2half(v0));
    const unsigned int hi = (unsigned int)__half_as_ushort(__float2half(v1));
    tile[cp][px] = lo | (hi << 16);
  }
  __syncthreads();

  const int cpair = tid & 31;
  const int pr0   = tid >> 5;
#pragma unroll
  for (int i = 0; i < 8; ++i) {
    const int p = pr0 + i * 8;
    *(unsigned int*)(dst + (size_t)(p0 + p) * CG_ + 2 * cpair) = tile[cpair][p];
  }
}

// ---------------------------------------------------------------------------
// Kernel 2: deformable sampling from [B,G,HW,CG] fp16.
//   1D grid 2048, XCD-swizzled so each XCD owns 4 contiguous bg slabs
//   (bg-major, ho-minor) -> gather rows stay L2-resident.
//   256 threads = 8 channel-octets x 32 wi; 2 pixels/thread (wi, wi+32).
//   Tap-level software pipeline: load tap k+1's 8 corners while FMA-ing tap k.
// ---------------------------------------------------------------------------
union DeformSM {
  struct { int4 o[576]; float4 w[576]; } p;  // 18432 B
  float ot[64][65];                          // 16640 B
};

__device__ __forceinline__ float4 ld16(const char* p, int off) {
  return *(const float4*)(p + off);
}

__global__ __launch_bounds__(256, 4) void deform_g16(const __half* __restrict__ x,
                                                     const float* __restrict__ off,
                                                     const float* __restrict__ msk,
                                                     float* __restrict__ out) {
  __shared__ DeformSM sm;

  // XCD-aware swizzle: XCD i (= orig % 8 round-robin) gets contiguous chunk.
  const int orig = blockIdx.x;                    // 0..2047
  const int wgid = (orig & 7) * 256 + (orig >> 3);
  const int ho = wgid & 63;
  const int bg = wgid >> 6;                       // bg-major within XCD chunk
  const int b  = bg >> 2;
  const int g  = bg & 3;
  const int tid = threadIdx.x;

  // ---- phase 1: params for 64 pixels x 9 taps ----
  for (int e = tid; e < 576; e += 256) {
    const int px = e & 63;
    const int k  = e >> 6;
    const int ky = k / 3, kx = k - ky * 3;
    const int och = (g * K_ + k) * 2;
    const size_t ob = ((size_t)(b * (2 * G_ * K_) + och) * HW_) + ho * W_ + px;
    const float dy = off[ob];
    const float dx = off[ob + HW_];
    const float m  = msk[((size_t)(b * (G_ * K_) + g * K_ + k) * HW_) + ho * W_ + px];

    const float py  = (float)(ho - 1 + ky) + dy;
    const float pxx = (float)(px - 1 + kx) + dx;
    const float fy = floorf(py), fx = floorf(pxx);
    const int y0 = (int)fy, x0 = (int)fx;
    const int y1 = y0 + 1,  x1 = x0 + 1;
    const float ly = py - fy, lx = pxx - fx;

    const bool vy0 = ((unsigned)y0 < (unsigned)H_), vy1 = ((unsigned)y1 < (unsigned)H_);
    const bool vx0 = ((unsigned)x0 < (unsigned)W_), vx1 = ((unsigned)x1 < (unsigned)W_);
    const float wy0 = (1.f - ly) * m, wy1 = ly * m;

    float4 w;
    w.x = (vy0 && vx0) ? wy0 * (1.f - lx) : 0.f;
    w.y = (vy0 && vx1) ? wy0 * lx         : 0.f;
    w.z = (vy1 && vx0) ? wy1 * (1.f - lx) : 0.f;
    w.w = (vy1 && vx1) ? wy1 * lx         : 0.f;

    const int y0c = min(max(y0, 0), H_ - 1), y1c = min(max(y1, 0), H_ - 1);
    const int x0c = min(max(x0, 0), W_ - 1), x1c = min(max(x1, 0), W_ - 1);

    int4 o;  // BYTE offsets into group slab (pix * CG * 2 = pix << 7)
    o.x = (y0c * W_ + x0c) << 7;
    o.y = (y0c * W_ + x1c) << 7;
    o.z = (y1c * W_ + x0c) << 7;
    o.w = (y1c * W_ + x1c) << 7;
    sm.p.o[e] = o;
    sm.p.w[e] = w;
  }
  __syncthreads();

  // ---- phase 2: 2 pixels x 8 channels per thread, pipelined over taps ----
  const int ci = tid & 7;
  const int wi = tid >> 3;
  const char* xb = (const char*)x + (size_t)(b * G_ + g) * HW_ * CG_ * 2 + ci * 16;

  float a0[8] = {0.f, 0.f, 0.f, 0.f, 0.f, 0.f, 0.f, 0.f};
  float a1[8] = {0.f, 0.f, 0.f, 0.f, 0.f, 0.f, 0.f, 0.f};

  // prologue: tap 0
  float4 wA = sm.p.w[wi],      wB = sm.p.w[wi + 32];
  int4   oA = sm.p.o[wi],      oB = sm.p.o[wi + 32];
  float4 rA0 = ld16(xb, oA.x), rA1 = ld16(xb, oA.y);
  float4 rA2 = ld16(xb, oA.z), rA3 = ld16(xb, oA.w);
  float4 rB0 = ld16(xb, oB.x), rB1 = ld16(xb, oB.y);
  float4 rB2 = ld16(xb, oB.z), rB3 = ld16(xb, oB.w);

#pragma unroll
  for (int k = 0; k < 9; ++k) {
    float4 nA0, nA1, nA2, nA3, nB0, nB1, nB2, nB3, nwA, nwB;
    if (k < 8) {  // prefetch tap k+1 (compile-time branch, fully unrolled)
      const int e = (k + 1) * 64 + wi;
      const int4 noA = sm.p.o[e];
      const int4 noB = sm.p.o[e + 32];
      nwA = sm.p.w[e];
      nwB = sm.p.w[e + 32];
      nA0 = ld16(xb, noA.x); nA1 = ld16(xb, noA.y);
      nA2 = ld16(xb, noA.z); nA3 = ld16(xb, noA.w);
      nB0 = ld16(xb, noB.x); nB1 = ld16(xb, noB.y);
      nB2 = ld16(xb, noB.z); nB3 = ld16(xb, noB.w);
    }

    const __half* hA0 = (const __half*)&rA0;
    const __half* hA1 = (const __half*)&rA1;
    const __half* hA2 = (const __half*)&rA2;
    const __half* hA3 = (const __half*)&rA3;
    const __half* hB0 = (const __half*)&rB0;
    const __half* hB1 = (const __half*)&rB1;
    const __half* hB2 = (const __half*)&rB2;
    const __half* hB3 = (const __half*)&rB3;
#pragma unroll
    for (int j = 0; j < 8; ++j) {
      float s0 = a0[j];
      s0 = fmaf(wA.x, __half2float(hA0[j]), s0);
      s0 = fmaf(wA.y, __half2float(hA1[j]), s0);
      s0 = fmaf(wA.z, __half2float(hA2[j]), s0);
      s0 = fmaf(wA.w, __half2float(hA3[j]), s0);
      a0[j] = s0;
      float s1 = a1[j];
      s1 = fmaf(wB.x, __half2float(hB0[j]), s1);
      s1 = fmaf(wB.y, __half2float(hB1[j]), s1);
      s1 = fmaf(wB.z, __half2float(hB2[j]), s1);
      s1 = fmaf(wB.w, __half2float(hB3[j]), s1);
      a1[j] = s1;
    }

    if (k < 8) {
      rA0 = nA0; rA1 = nA1; rA2 = nA2; rA3 = nA3;
      rB0 = nB0; rB1 = nB1; rB2 = nB2; rB3 = nB3;
      wA = nwA; wB = nwB;
    }
  }

  __syncthreads();  // params dead; reuse LDS as staging tile
#pragma unroll
  for (int j = 0; j < 8; ++j) {
    sm.ot[ci * 8 + j][wi]      = a0[j];
    sm.ot[ci * 8 + j][wi + 32] = a1[j];
  }
  __syncthreads();

  // ---- phase 3: coalesced store, 64 lanes x 4B = 256B per row ----
  float* ob = out + ((size_t)(b * C_ + g * CG_)) * HW_ + ho * W_;
  const int lane = tid & 63;
  const int r0   = tid >> 6;
#pragma unroll
  for (int q = 0; q < 16; ++q) {
    const int c = q * 4 + r0;
    ob[(size_t)c * HW_ + lane] = sm.ot[c][lane];
  }
}

// ---------------------------------------------------------------------------
// Fallback (no workspace): fp32 NCHW gathers, 4 ch/thread.
// ---------------------------------------------------------------------------
__global__ __launch_bounds__(256) void deform_f32_nchw(const float* __restrict__ x,
                                                       const float* __restrict__ off,
                                                       const float* __restrict__ msk,
                                                       float* __restrict__ out) {
  __shared__ int4   s_o[144];
  __shared__ float4 s_w[144];
  const int woq = blockIdx.x;
  const int ho  = blockIdx.y;
  const int b   = blockIdx.z >> 2;
  const int g   = blockIdx.z & 3;
  const int tid = threadIdx.x;

  if (tid < 144) {
    const int wi = tid / 9, k = tid - wi * 9;
    const int wo = woq * 16 + wi;
    const int ky = k / 3, kx = k - ky * 3;
    const int och = (g * K_ + k) * 2;
    const size_t ob = ((size_t)(b * (2 * G_ * K_) + och) * H_ + ho) * W_ + wo;
    const float dy = off[ob];
    const float dx = off[ob + HW_];
    const float m  = msk[((size_t)(b * (G_ * K_) + g * K_ + k) * H_ + ho) * W_ + wo];
    const float py = (float)(ho - 1 + ky) + dy;
    const float px = (float)(wo - 1 + kx) + dx;
    const float fy = floorf(py), fx = floorf(px);
    const int y0 = (int)fy, x0 = (int)fx;
    const int y1 = y0 + 1,  x1 = x0 + 1;
    const float ly = py - fy, lx = px - fx;
    const bool vy0 = ((unsigned)y0 < (unsigned)H_), vy1 = ((unsigned)y1 < (unsigned)H_);
    const bool vx0 = ((unsigned)x0 < (unsigned)W_), vx1 = ((unsigned)x1 < (unsigned)W_);
    const float wy0 = (1.f - ly) * m, wy1 = ly * m;
    float4 w;
    w.x = (vy0 && vx0) ? wy0 * (1.f - lx) : 0.f;
    w.y = (vy0 && vx1) ? wy0 * lx         : 0.f;
    w.z = (vy1 && vx0) ? wy1 * (1.f - lx) : 0.f;
    w.w = (vy1 && vx1) ? wy1 * lx         : 0.f;
    const int y0c = min(max(y0, 0), H_ - 1), y1c = min(max(y1, 0), H_ - 1);
    const int x0c = min(max(x0, 0), W_ - 1), x1c = min(max(x1, 0), W_ - 1);
    s_o[tid] = make_int4(y0c * W_ + x0c, y0c * W_ + x1c, y1c * W_ + x0c, y1c * W_ + x1c);
    s_w[tid] = w;
  }
  __syncthreads();

  const int ci = tid & 15, wi = tid >> 4;
  const float* xb = x + (size_t)(b * C_ + g * CG_ + ci * 4) * HW_;
  float a0 = 0.f, a1 = 0.f, a2 = 0.f, a3 = 0.f;
#pragma unroll
  for (int k = 0; k < 9; ++k) {
    const int e = wi * 9 + k;
    const int4   o = s_o[e];
    const float4 w = s_w[e];
    a0 += w.x * xb[o.x] + w.y * xb[o.y] + w.z * xb[o.z] + w.w * xb[o.w];
    const float* x1p = xb + HW_;
    a1 += w.x * x1p[o.x] + w.y * x1p[o.y] + w.z * x1p[o.z] + w.w * x1p[o.w];
    const float* x2p = xb + 2 * HW_;
    a2 += w.x * x2p[o.x] + w.y * x2p[o.y] + w.z * x2p[o.z] + w.w * x2p[o.w];
    const float* x3p = xb + 3 * HW_;
    a3 += w.x * x3p[o.x] + w.y * x3p[o.y] + w.z * x3p[o.z] + w.w * x3p[o.w];
  }
  float* ob = out + ((size_t)(b * C_ + g * CG_ + ci * 4)) * HW_ + ho * W_ + woq * 16 + wi;
  ob[0] = a0; ob[HW_] = a1; ob[2 * HW_] = a2; ob[3 * HW_] = a3;
}

// ---------------------------------------------------------------------------
extern "C" void kernel_launch(void* const* d_in, const int* in_sizes, int n_in,
                              void* d_out, int out_size, void* d_ws, size_t ws_size,
                              hipStream_t stream) {
  const float* inp = (const float*)d_in[0];
  const float* off = (const float*)d_in[1];
  const float* msk = (const float*)d_in[2];
  float* out = (float*)d_out;

  const size_t need = (size_t)B_ * C_ * HW_ * sizeof(__half);  // 16.8 MB
  if (ws_size >= need) {
    __half* xt = (__half*)d_ws;
    to_ghwc_f16<<<dim3(HW_ / 64, G_, B_), 256, 0, stream>>>(inp, xt);
    deform_g16<<<dim3(H_ * B_ * G_), 256, 0, stream>>>(xt, off, msk, out);
  } else {
    deform_f32_nchw<<<dim3(4, H_, B_ * G_), 256, 0, stream>>>(inp, off, msk, out);
  }
}

// Round 5
// 39.037 us; speedup vs baseline: 2.6513x; 2.6513x over previous
//
#include <hip/hip_runtime.h>
#include <hip/hip_fp16.h>

#define B_  8
#define C_  256
#define H_  64
#define W_  64
#define G_  4
#define CG_ 64
#define K_  9
#define HW_ (H_ * W_)  // 4096

// ---------------------------------------------------------------------------
// Kernel 1: NCHW fp32 -> group-major NHWC fp16  [B,C,HW] -> [B,G,HW,CG]
// ---------------------------------------------------------------------------
__global__ __launch_bounds__(256) void to_ghwc_f16(const float* __restrict__ in,
                                                   __half* __restrict__ out) {
  __shared__ unsigned int tile[32][65];  // [channel-pair][pixel]
  const int b  = blockIdx.z;
  const int p0 = blockIdx.x * 64;
  const int g  = blockIdx.y;
  const int tid = threadIdx.x;
  const float* src = in + (size_t)b * C_ * HW_ + (size_t)g * CG_ * HW_;
  __half* dst = out + ((size_t)(b * G_ + g) * HW_) * CG_;

  const int px  = tid & 63;
  const int cp0 = tid >> 6;
#pragma unroll
  for (int i = 0; i < 8; ++i) {
    const int cp = cp0 + i * 4;
    const int c  = cp * 2;
    const float v0 = src[(size_t)c * HW_ + p0 + px];
    const float v1 = src[(size_t)(c + 1) * HW_ + p0 + px];
    const unsigned int lo = (unsigned int)__half_as_ushort(__float2half(v0));
    const unsigned int hi = (unsigned int)__half_as_ushort(__float2half(v1));
    tile[cp][px] = lo | (hi << 16);
  }
  __syncthreads();

  const int cpair = tid & 31;
  const int pr0   = tid >> 5;
#pragma unroll
  for (int i = 0; i < 8; ++i) {
    const int p = pr0 + i * 8;
    *(unsigned int*)(dst + (size_t)(p0 + p) * CG_ + 2 * cpair) = tile[cpair][p];
  }
}

// ---------------------------------------------------------------------------
// Kernel 2: deformable sampling from [B,G,HW,CG] fp16.
//   1D grid 2048, XCD-swizzled (bg-major per XCD) -> per-XCD working set
//   (4 input slabs = 2 MB + params) fits the 4 MB L2: FETCH ~= compulsory.
//   256 threads = 8 channel-octets x 32 wi; 2 pixels/thread (wi, wi+32).
//   Gathers use uniform SGPR base + 32-bit voffset (saddr form): 1 addr
//   VGPR per load; 8 independent 16B loads per tap; compiler-scheduled.
// ---------------------------------------------------------------------------
union DeformSM {
  struct { int4 o[576]; float4 w[576]; } p;  // 18432 B
  float ot[64][65];                          // 16640 B
};

__global__ __launch_bounds__(256, 4) void deform_g16(const __half* __restrict__ x,
                                                     const float* __restrict__ off,
                                                     const float* __restrict__ msk,
                                                     float* __restrict__ out) {
  __shared__ DeformSM sm;

  // XCD-aware swizzle: grid 2048 % 8 == 0; XCD i owns contiguous bg slabs.
  const int orig = blockIdx.x;                    // 0..2047
  const int wgid = (orig & 7) * 256 + (orig >> 3);
  const int ho = wgid & 63;
  const int bg = wgid >> 6;
  const int b  = bg >> 2;
  const int g  = bg & 3;
  const int tid = threadIdx.x;

  // ---- phase 1: params for 64 pixels x 9 taps ----
  for (int e = tid; e < 576; e += 256) {
    const int px = e & 63;
    const int k  = e >> 6;
    const int ky = k / 3, kx = k - ky * 3;
    const int och = (g * K_ + k) * 2;
    const size_t ob = ((size_t)(b * (2 * G_ * K_) + och) * HW_) + ho * W_ + px;
    const float dy = off[ob];
    const float dx = off[ob + HW_];
    const float m  = msk[((size_t)(b * (G_ * K_) + g * K_ + k) * HW_) + ho * W_ + px];

    const float py  = (float)(ho - 1 + ky) + dy;
    const float pxx = (float)(px - 1 + kx) + dx;
    const float fy = floorf(py), fx = floorf(pxx);
    const int y0 = (int)fy, x0 = (int)fx;
    const int y1 = y0 + 1,  x1 = x0 + 1;
    const float ly = py - fy, lx = pxx - fx;

    const bool vy0 = ((unsigned)y0 < (unsigned)H_), vy1 = ((unsigned)y1 < (unsigned)H_);
    const bool vx0 = ((unsigned)x0 < (unsigned)W_), vx1 = ((unsigned)x1 < (unsigned)W_);
    const float wy0 = (1.f - ly) * m, wy1 = ly * m;

    float4 w;
    w.x = (vy0 && vx0) ? wy0 * (1.f - lx) : 0.f;
    w.y = (vy0 && vx1) ? wy0 * lx         : 0.f;
    w.z = (vy1 && vx0) ? wy1 * (1.f - lx) : 0.f;
    w.w = (vy1 && vx1) ? wy1 * lx         : 0.f;

    const int y0c = min(max(y0, 0), H_ - 1), y1c = min(max(y1, 0), H_ - 1);
    const int x0c = min(max(x0, 0), W_ - 1), x1c = min(max(x1, 0), W_ - 1);

    int4 o;  // BYTE offsets into group slab (pix * CG * 2 = pix << 7)
    o.x = (y0c * W_ + x0c) << 7;
    o.y = (y0c * W_ + x1c) << 7;
    o.z = (y1c * W_ + x0c) << 7;
    o.w = (y1c * W_ + x1c) << 7;
    sm.p.o[e] = o;
    sm.p.w[e] = w;
  }
  __syncthreads();

  // ---- phase 2: 2 pixels x 8 channels per thread ----
  const int ci16 = (tid & 7) * 16;   // byte offset of channel octet
  const int wi   = tid >> 3;         // 0..31; pixels wi and wi+32
  // uniform SGPR base: the group slab
  const char* base = (const char*)x + (size_t)(b * G_ + g) * (HW_ * CG_ * 2);

  float a0[8] = {0.f, 0.f, 0.f, 0.f, 0.f, 0.f, 0.f, 0.f};
  float a1[8] = {0.f, 0.f, 0.f, 0.f, 0.f, 0.f, 0.f, 0.f};

#pragma unroll
  for (int k = 0; k < 9; ++k) {
    const int4   oA = sm.p.o[k * 64 + wi];
    const float4 wA = sm.p.w[k * 64 + wi];
    const int4   oB = sm.p.o[k * 64 + wi + 32];
    const float4 wB = sm.p.w[k * 64 + wi + 32];

    const float4 rA0 = *(const float4*)(base + (oA.x + ci16));
    const float4 rA1 = *(const float4*)(base + (oA.y + ci16));
    const float4 rA2 = *(const float4*)(base + (oA.z + ci16));
    const float4 rA3 = *(const float4*)(base + (oA.w + ci16));
    const float4 rB0 = *(const float4*)(base + (oB.x + ci16));
    const float4 rB1 = *(const float4*)(base + (oB.y + ci16));
    const float4 rB2 = *(const float4*)(base + (oB.z + ci16));
    const float4 rB3 = *(const float4*)(base + (oB.w + ci16));

    const __half* hA0 = (const __half*)&rA0;
    const __half* hA1 = (const __half*)&rA1;
    const __half* hA2 = (const __half*)&rA2;
    const __half* hA3 = (const __half*)&rA3;
    const __half* hB0 = (const __half*)&rB0;
    const __half* hB1 = (const __half*)&rB1;
    const __half* hB2 = (const __half*)&rB2;
    const __half* hB3 = (const __half*)&rB3;
#pragma unroll
    for (int j = 0; j < 8; ++j) {
      float s0 = a0[j];
      s0 = fmaf(wA.x, __half2float(hA0[j]), s0);
      s0 = fmaf(wA.y, __half2float(hA1[j]), s0);
      s0 = fmaf(wA.z, __half2float(hA2[j]), s0);
      s0 = fmaf(wA.w, __half2float(hA3[j]), s0);
      a0[j] = s0;
      float s1 = a1[j];
      s1 = fmaf(wB.x, __half2float(hB0[j]), s1);
      s1 = fmaf(wB.y, __half2float(hB1[j]), s1);
      s1 = fmaf(wB.z, __half2float(hB2[j]), s1);
      s1 = fmaf(wB.w, __half2float(hB3[j]), s1);
      a1[j] = s1;
    }
  }

  __syncthreads();  // params dead; reuse LDS as staging tile
#pragma unroll
  for (int j = 0; j < 8; ++j) {
    const int ci = tid & 7;
    sm.ot[ci * 8 + j][wi]      = a0[j];
    sm.ot[ci * 8 + j][wi + 32] = a1[j];
  }
  __syncthreads();

  // ---- phase 3: coalesced store, 64 lanes x 4B = 256B per row ----
  float* ob = out + ((size_t)(b * C_ + g * CG_)) * HW_ + ho * W_;
  const int lane = tid & 63;
  const int r0   = tid >> 6;
#pragma unroll
  for (int q = 0; q < 16; ++q) {
    const int c = q * 4 + r0;
    ob[(size_t)c * HW_ + lane] = sm.ot[c][lane];
  }
}

// ---------------------------------------------------------------------------
// Fallback (no workspace): fp32 NCHW gathers, 4 ch/thread.
// ---------------------------------------------------------------------------
__global__ __launch_bounds__(256) void deform_f32_nchw(const float* __restrict__ x,
                                                       const float* __restrict__ off,
                                                       const float* __restrict__ msk,
                                                       float* __restrict__ out) {
  __shared__ int4   s_o[144];
  __shared__ float4 s_w[144];
  const int woq = blockIdx.x;
  const int ho  = blockIdx.y;
  const int b   = blockIdx.z >> 2;
  const int g   = blockIdx.z & 3;
  const int tid = threadIdx.x;

  if (tid < 144) {
    const int wi = tid / 9, k = tid - wi * 9;
    const int wo = woq * 16 + wi;
    const int ky = k / 3, kx = k - ky * 3;
    const int och = (g * K_ + k) * 2;
    const size_t ob = ((size_t)(b * (2 * G_ * K_) + och) * H_ + ho) * W_ + wo;
    const float dy = off[ob];
    const float dx = off[ob + HW_];
    const float m  = msk[((size_t)(b * (G_ * K_) + g * K_ + k) * H_ + ho) * W_ + wo];
    const float py = (float)(ho - 1 + ky) + dy;
    const float px = (float)(wo - 1 + kx) + dx;
    const float fy = floorf(py), fx = floorf(px);
    const int y0 = (int)fy, x0 = (int)fx;
    const int y1 = y0 + 1,  x1 = x0 + 1;
    const float ly = py - fy, lx = px - fx;
    const bool vy0 = ((unsigned)y0 < (unsigned)H_), vy1 = ((unsigned)y1 < (unsigned)H_);
    const bool vx0 = ((unsigned)x0 < (unsigned)W_), vx1 = ((unsigned)x1 < (unsigned)W_);
    const float wy0 = (1.f - ly) * m, wy1 = ly * m;
    float4 w;
    w.x = (vy0 && vx0) ? wy0 * (1.f - lx) : 0.f;
    w.y = (vy0 && vx1) ? wy0 * lx         : 0.f;
    w.z = (vy1 && vx0) ? wy1 * (1.f - lx) : 0.f;
    w.w = (vy1 && vx1) ? wy1 * lx         : 0.f;
    const int y0c = min(max(y0, 0), H_ - 1), y1c = min(max(y1, 0), H_ - 1);
    const int x0c = min(max(x0, 0), W_ - 1), x1c = min(max(x1, 0), W_ - 1);
    s_o[tid] = make_int4(y0c * W_ + x0c, y0c * W_ + x1c, y1c * W_ + x0c, y1c * W_ + x1c);
    s_w[tid] = w;
  }
  __syncthreads();

  const int ci = tid & 15, wi = tid >> 4;
  const float* xb = x + (size_t)(b * C_ + g * CG_ + ci * 4) * HW_;
  float a0 = 0.f, a1 = 0.f, a2 = 0.f, a3 = 0.f;
#pragma unroll
  for (int k = 0; k < 9; ++k) {
    const int e = wi * 9 + k;
    const int4   o = s_o[e];
    const float4 w = s_w[e];
    a0 += w.x * xb[o.x] + w.y * xb[o.y] + w.z * xb[o.z] + w.w * xb[o.w];
    const float* x1p = xb + HW_;
    a1 += w.x * x1p[o.x] + w.y * x1p[o.y] + w.z * x1p[o.z] + w.w * x1p[o.w];
    const float* x2p = xb + 2 * HW_;
    a2 += w.x * x2p[o.x] + w.y * x2p[o.y] + w.z * x2p[o.z] + w.w * x2p[o.w];
    const float* x3p = xb + 3 * HW_;
    a3 += w.x * x3p[o.x] + w.y * x3p[o.y] + w.z * x3p[o.z] + w.w * x3p[o.w];
  }
  float* ob = out + ((size_t)(b * C_ + g * CG_ + ci * 4)) * HW_ + ho * W_ + woq * 16 + wi;
  ob[0] = a0; ob[HW_] = a1; ob[2 * HW_] = a2; ob[3 * HW_] = a3;
}

// ---------------------------------------------------------------------------
extern "C" void kernel_launch(void* const* d_in, const int* in_sizes, int n_in,
                              void* d_out, int out_size, void* d_ws, size_t ws_size,
                              hipStream_t stream) {
  const float* inp = (const float*)d_in[0];
  const float* off = (const float*)d_in[1];
  const float* msk = (const float*)d_in[2];
  float* out = (float*)d_out;

  const size_t need = (size_t)B_ * C_ * HW_ * sizeof(__half);  // 16.8 MB
  if (ws_size >= need) {
    __half* xt = (__half*)d_ws;
    to_ghwc_f16<<<dim3(HW_ / 64, G_, B_), 256, 0, stream>>>(inp, xt);
    deform_g16<<<dim3(H_ * B_ * G_), 256, 0, stream>>>(xt, off, msk, out);
  } else {
    deform_f32_nchw<<<dim3(4, H_, B_ * G_), 256, 0, stream>>>(inp, off, msk, out);
  }
}

// Round 6
// 38.229 us; speedup vs baseline: 2.7073x; 1.0211x over previous
//
#include <hip/hip_runtime.h>
#include <hip/hip_fp16.h>

#define B_  8
#define C_  256
#define H_  64
#define W_  64
#define G_  4
#define CG_ 64
#define K_  9
#define HW_ (H_ * W_)  // 4096

// ---------------------------------------------------------------------------
// Kernel 1: NCHW fp32 -> group-major NHWC fp16  [B,C,HW] -> [B,G,HW,CG]
// ---------------------------------------------------------------------------
__global__ __launch_bounds__(256) void to_ghwc_f16(const float* __restrict__ in,
                                                   __half* __restrict__ out) {
  __shared__ unsigned int tile[32][65];  // [channel-pair][pixel]
  const int b  = blockIdx.z;
  const int p0 = blockIdx.x * 64;
  const int g  = blockIdx.y;
  const int tid = threadIdx.x;
  const float* src = in + (size_t)b * C_ * HW_ + (size_t)g * CG_ * HW_;
  __half* dst = out + ((size_t)(b * G_ + g) * HW_) * CG_;

  const int px  = tid & 63;
  const int cp0 = tid >> 6;
#pragma unroll
  for (int i = 0; i < 8; ++i) {
    const int cp = cp0 + i * 4;
    const int c  = cp * 2;
    const float v0 = src[(size_t)c * HW_ + p0 + px];
    const float v1 = src[(size_t)(c + 1) * HW_ + p0 + px];
    const unsigned int lo = (unsigned int)__half_as_ushort(__float2half(v0));
    const unsigned int hi = (unsigned int)__half_as_ushort(__float2half(v1));
    tile[cp][px] = lo | (hi << 16);
  }
  __syncthreads();

  const int cpair = tid & 31;
  const int pr0   = tid >> 5;
#pragma unroll
  for (int i = 0; i < 8; ++i) {
    const int p = pr0 + i * 8;
    *(unsigned int*)(dst + (size_t)(p0 + p) * CG_ + 2 * cpair) = tile[cpair][p];
  }
}

// ---------------------------------------------------------------------------
// Kernel 2: deformable sampling from [B,G,HW,CG] fp16.
//   Each block: one (b,g) and a 4x16 output tile (TH=4 rows x TW=16 cols).
//   2D tile shrinks the block's gather footprint to ~24 KB -> L1-resident,
//   capturing the heavy corner-line reuse across neighboring pixels/taps.
//   XCD swizzle: bg-major per XCD -> input slab (2 MB) stays L2-resident.
//   256 threads = 8 channel-octets x 32 slots; 2 pixels/slot (px, px+32).
//   Gathers: uniform SGPR base + 32-bit voffset (saddr form).
// ---------------------------------------------------------------------------
union DeformSM {
  struct { int4 o[576]; float4 w[576]; } p;  // 18432 B
  float ot[64][65];                          // 16640 B
};

__global__ __launch_bounds__(256, 4) void deform_g16(const __half* __restrict__ x,
                                                     const float* __restrict__ off,
                                                     const float* __restrict__ msk,
                                                     float* __restrict__ out) {
  __shared__ DeformSM sm;

  // XCD-aware swizzle: grid 2048 % 8 == 0; XCD i owns contiguous bg slabs.
  const int orig = blockIdx.x;                    // 0..2047
  const int wgid = (orig & 7) * 256 + (orig >> 3);
  const int tile = wgid & 63;                     // 64 tiles per (b,g)
  const int bg   = wgid >> 6;
  const int ho0  = (tile >> 2) * 4;               // 16 row-tiles
  const int wo0  = (tile & 3) * 16;               // 4 col-tiles
  const int b    = bg >> 2;
  const int g    = bg & 3;
  const int tid  = threadIdx.x;

  // ---- phase 1: params for 64 tile pixels x 9 taps ----
  for (int e = tid; e < 576; e += 256) {
    const int px  = e & 63;           // local pixel id: row*16+col
    const int k   = e >> 6;
    const int row = px >> 4, col = px & 15;
    const int ho  = ho0 + row, wo = wo0 + col;
    const int ky = k / 3, kx = k - ky * 3;
    const int och = (g * K_ + k) * 2;
    const size_t ob = ((size_t)(b * (2 * G_ * K_) + och) * HW_) + ho * W_ + wo;
    const float dy = off[ob];
    const float dx = off[ob + HW_];
    const float m  = msk[((size_t)(b * (G_ * K_) + g * K_ + k) * HW_) + ho * W_ + wo];

    const float py  = (float)(ho - 1 + ky) + dy;
    const float pxx = (float)(wo - 1 + kx) + dx;
    const float fy = floorf(py), fx = floorf(pxx);
    const int y0 = (int)fy, x0 = (int)fx;
    const int y1 = y0 + 1,  x1 = x0 + 1;
    const float ly = py - fy, lx = pxx - fx;

    const bool vy0 = ((unsigned)y0 < (unsigned)H_), vy1 = ((unsigned)y1 < (unsigned)H_);
    const bool vx0 = ((unsigned)x0 < (unsigned)W_), vx1 = ((unsigned)x1 < (unsigned)W_);
    const float wy0 = (1.f - ly) * m, wy1 = ly * m;

    float4 w;
    w.x = (vy0 && vx0) ? wy0 * (1.f - lx) : 0.f;
    w.y = (vy0 && vx1) ? wy0 * lx         : 0.f;
    w.z = (vy1 && vx0) ? wy1 * (1.f - lx) : 0.f;
    w.w = (vy1 && vx1) ? wy1 * lx         : 0.f;

    const int y0c = min(max(y0, 0), H_ - 1), y1c = min(max(y1, 0), H_ - 1);
    const int x0c = min(max(x0, 0), W_ - 1), x1c = min(max(x1, 0), W_ - 1);

    int4 o;  // BYTE offsets into group slab (pix * CG * 2 = pix << 7)
    o.x = (y0c * W_ + x0c) << 7;
    o.y = (y0c * W_ + x1c) << 7;
    o.z = (y1c * W_ + x0c) << 7;
    o.w = (y1c * W_ + x1c) << 7;
    sm.p.o[e] = o;
    sm.p.w[e] = w;
  }
  __syncthreads();

  // ---- phase 2: 2 tile-pixels x 8 channels per thread ----
  const int ci16 = (tid & 7) * 16;   // byte offset of channel octet
  const int wi   = tid >> 3;         // slot 0..31; pixels wi and wi+32
  const char* base = (const char*)x + (size_t)(b * G_ + g) * (HW_ * CG_ * 2);

  float a0[8] = {0.f, 0.f, 0.f, 0.f, 0.f, 0.f, 0.f, 0.f};
  float a1[8] = {0.f, 0.f, 0.f, 0.f, 0.f, 0.f, 0.f, 0.f};

#pragma unroll
  for (int k = 0; k < 9; ++k) {
    const int4   oA = sm.p.o[k * 64 + wi];
    const float4 wA = sm.p.w[k * 64 + wi];
    const int4   oB = sm.p.o[k * 64 + wi + 32];
    const float4 wB = sm.p.w[k * 64 + wi + 32];

    const float4 rA0 = *(const float4*)(base + (oA.x + ci16));
    const float4 rA1 = *(const float4*)(base + (oA.y + ci16));
    const float4 rA2 = *(const float4*)(base + (oA.z + ci16));
    const float4 rA3 = *(const float4*)(base + (oA.w + ci16));
    const float4 rB0 = *(const float4*)(base + (oB.x + ci16));
    const float4 rB1 = *(const float4*)(base + (oB.y + ci16));
    const float4 rB2 = *(const float4*)(base + (oB.z + ci16));
    const float4 rB3 = *(const float4*)(base + (oB.w + ci16));

    const __half* hA0 = (const __half*)&rA0;
    const __half* hA1 = (const __half*)&rA1;
    const __half* hA2 = (const __half*)&rA2;
    const __half* hA3 = (const __half*)&rA3;
    const __half* hB0 = (const __half*)&rB0;
    const __half* hB1 = (const __half*)&rB1;
    const __half* hB2 = (const __half*)&rB2;
    const __half* hB3 = (const __half*)&rB3;
#pragma unroll
    for (int j = 0; j < 8; ++j) {
      float s0 = a0[j];
      s0 = fmaf(wA.x, __half2float(hA0[j]), s0);
      s0 = fmaf(wA.y, __half2float(hA1[j]), s0);
      s0 = fmaf(wA.z, __half2float(hA2[j]), s0);
      s0 = fmaf(wA.w, __half2float(hA3[j]), s0);
      a0[j] = s0;
      float s1 = a1[j];
      s1 = fmaf(wB.x, __half2float(hB0[j]), s1);
      s1 = fmaf(wB.y, __half2float(hB1[j]), s1);
      s1 = fmaf(wB.z, __half2float(hB2[j]), s1);
      s1 = fmaf(wB.w, __half2float(hB3[j]), s1);
      a1[j] = s1;
    }
  }

  __syncthreads();  // params dead; reuse LDS as staging tile
  {
    const int ci = tid & 7;
#pragma unroll
    for (int j = 0; j < 8; ++j) {
      sm.ot[ci * 8 + j][wi]      = a0[j];
      sm.ot[ci * 8 + j][wi + 32] = a1[j];
    }
  }
  __syncthreads();

  // ---- phase 3: stores; wave covers 64 px of one channel = 4 x 64B segs ----
  float* ob = out + ((size_t)(b * C_ + g * CG_)) * HW_;
#pragma unroll
  for (int q = 0; q < 16; ++q) {
    const int flat = q * 256 + tid;
    const int c  = flat >> 6;          // uniform across a wave
    const int px = flat & 63;
    const int ho = ho0 + (px >> 4), wo = wo0 + (px & 15);
    ob[(size_t)c * HW_ + ho * W_ + wo] = sm.ot[c][px];
  }
}

// ---------------------------------------------------------------------------
// Fallback (no workspace): fp32 NCHW gathers, 4 ch/thread.
// ---------------------------------------------------------------------------
__global__ __launch_bounds__(256) void deform_f32_nchw(const float* __restrict__ x,
                                                       const float* __restrict__ off,
                                                       const float* __restrict__ msk,
                                                       float* __restrict__ out) {
  __shared__ int4   s_o[144];
  __shared__ float4 s_w[144];
  const int woq = blockIdx.x;
  const int ho  = blockIdx.y;
  const int b   = blockIdx.z >> 2;
  const int g   = blockIdx.z & 3;
  const int tid = threadIdx.x;

  if (tid < 144) {
    const int wi = tid / 9, k = tid - wi * 9;
    const int wo = woq * 16 + wi;
    const int ky = k / 3, kx = k - ky * 3;
    const int och = (g * K_ + k) * 2;
    const size_t ob = ((size_t)(b * (2 * G_ * K_) + och) * H_ + ho) * W_ + wo;
    const float dy = off[ob];
    const float dx = off[ob + HW_];
    const float m  = msk[((size_t)(b * (G_ * K_) + g * K_ + k) * H_ + ho) * W_ + wo];
    const float py = (float)(ho - 1 + ky) + dy;
    const float px = (float)(wo - 1 + kx) + dx;
    const float fy = floorf(py), fx = floorf(px);
    const int y0 = (int)fy, x0 = (int)fx;
    const int y1 = y0 + 1,  x1 = x0 + 1;
    const float ly = py - fy, lx = px - fx;
    const bool vy0 = ((unsigned)y0 < (unsigned)H_), vy1 = ((unsigned)y1 < (unsigned)H_);
    const bool vx0 = ((unsigned)x0 < (unsigned)W_), vx1 = ((unsigned)x1 < (unsigned)W_);
    const float wy0 = (1.f - ly) * m, wy1 = ly * m;
    float4 w;
    w.x = (vy0 && vx0) ? wy0 * (1.f - lx) : 0.f;
    w.y = (vy0 && vx1) ? wy0 * lx         : 0.f;
    w.z = (vy1 && vx0) ? wy1 * (1.f - lx) : 0.f;
    w.w = (vy1 && vx1) ? wy1 * lx         : 0.f;
    const int y0c = min(max(y0, 0), H_ - 1), y1c = min(max(y1, 0), H_ - 1);
    const int x0c = min(max(x0, 0), W_ - 1), x1c = min(max(x1, 0), W_ - 1);
    s_o[tid] = make_int4(y0c * W_ + x0c, y0c * W_ + x1c, y1c * W_ + x0c, y1c * W_ + x1c);
    s_w[tid] = w;
  }
  __syncthreads();

  const int ci = tid & 15, wi = tid >> 4;
  const float* xb = x + (size_t)(b * C_ + g * CG_ + ci * 4) * HW_;
  float a0 = 0.f, a1 = 0.f, a2 = 0.f, a3 = 0.f;
#pragma unroll
  for (int k = 0; k < 9; ++k) {
    const int e = wi * 9 + k;
    const int4   o = s_o[e];
    const float4 w = s_w[e];
    a0 += w.x * xb[o.x] + w.y * xb[o.y] + w.z * xb[o.z] + w.w * xb[o.w];
    const float* x1p = xb + HW_;
    a1 += w.x * x1p[o.x] + w.y * x1p[o.y] + w.z * x1p[o.z] + w.w * x1p[o.w];
    const float* x2p = xb + 2 * HW_;
    a2 += w.x * x2p[o.x] + w.y * x2p[o.y] + w.z * x2p[o.z] + w.w * x2p[o.w];
    const float* x3p = xb + 3 * HW_;
    a3 += w.x * x3p[o.x] + w.y * x3p[o.y] + w.z * x3p[o.z] + w.w * x3p[o.w];
  }
  float* ob = out + ((size_t)(b * C_ + g * CG_ + ci * 4)) * HW_ + ho * W_ + woq * 16 + wi;
  ob[0] = a0; ob[HW_] = a1; ob[2 * HW_] = a2; ob[3 * HW_] = a3;
}

// ---------------------------------------------------------------------------
extern "C" void kernel_launch(void* const* d_in, const int* in_sizes, int n_in,
                              void* d_out, int out_size, void* d_ws, size_t ws_size,
                              hipStream_t stream) {
  const float* inp = (const float*)d_in[0];
  const float* off = (const float*)d_in[1];
  const float* msk = (const float*)d_in[2];
  float* out = (float*)d_out;

  const size_t need = (size_t)B_ * C_ * HW_ * sizeof(__half);  // 16.8 MB
  if (ws_size >= need) {
    __half* xt = (__half*)d_ws;
    to_ghwc_f16<<<dim3(HW_ / 64, G_, B_), 256, 0, stream>>>(inp, xt);
    deform_g16<<<dim3(H_ * B_ * G_), 256, 0, stream>>>(xt, off, msk, out);
  } else {
    deform_f32_nchw<<<dim3(4, H_, B_ * G_), 256, 0, stream>>>(inp, off, msk, out);
  }
}